// Round 9
// baseline (1381.184 us; speedup 1.0000x reference)
//
#include <hip/hip_runtime.h>
#include <math.h>

#define DIN 128
#define HID 16
#define DOUT 12
#define NMID 11

#define CPB 128        // cols per bucket (col >> 7)
#define NBMAX 800      // max coarse buckets (runtime 782)
#define EPB 4096       // edges per binning block
#define CAP 5120       // max edges per bucket in s4 LDS
#define CHK 256        // edges per layer-chunk (fused kernel block)
#define SPAN 512       // max edge span per chunk (CHK + maxdeg margin)

typedef unsigned long long ull;

// exclusive scan in place over arr[0..L), 256 threads, L <= 1024
__device__ __forceinline__ void scan4(int* arr, int L, int tid, int* wtot) {
    int lane = tid & 63, wid = tid >> 6;
    int v[4]; int s = 0;
#pragma unroll
    for (int j = 0; j < 4; ++j) {
        int idx = tid * 4 + j;
        int t = (idx < L) ? arr[idx] : 0;
        v[j] = s; s += t;
    }
    int x = s;
    for (int off = 1; off < 64; off <<= 1) {
        int y = __shfl_up(x, off, 64);
        if (lane >= off) x += y;
    }
    if (lane == 63) wtot[wid] = x;
    __syncthreads();
    if (tid == 0) { int c = 0; for (int i = 0; i < 4; ++i) { int t = wtot[i]; wtot[i] = c; c += t; } }
    __syncthreads();
    int b0 = wtot[wid] + (x - s);
#pragma unroll
    for (int j = 0; j < 4; ++j) {
        int idx = tid * 4 + j;
        if (idx < L) arr[idx] = b0 + v[j];
    }
    __syncthreads();
}

// S1: per-block coarse histogram + global bucket totals.
__global__ __launch_bounds__(256)
void s1_hist(const int* __restrict__ col, int* __restrict__ H, int* __restrict__ T,
             int E, int N, int NB) {
    __shared__ int hist[NBMAX];
    int tid = threadIdx.x;
    for (int i = tid; i < NB; i += 256) hist[i] = 0;
    __syncthreads();
    long base = (long)blockIdx.x * EPB;
    for (int r = 0; r < EPB / 256; ++r) {
        long e = base + r * 256 + tid;
        if (e < E) {
            int c = col[e];
            if ((unsigned)c < (unsigned)N) atomicAdd(&hist[c >> 7], 1);
        }
    }
    __syncthreads();
    for (int i = tid; i < NB; i += 256) {
        int h = hist[i];
        H[(long)blockIdx.x * NB + i] = h;
        if (h) atomicAdd(&T[i], h);
    }
}

// S2b: exclusive scan of bucket totals -> bStart[0..NB], single block.
__global__ __launch_bounds__(1024)
void s2b_scan(const int* __restrict__ T, int* __restrict__ bStart, int NB) {
    __shared__ int wtot[16];
    int tid = threadIdx.x, lane = tid & 63, wid = tid >> 6;
    int v = (tid < NB) ? T[tid] : 0;
    int x = v;
    for (int off = 1; off < 64; off <<= 1) {
        int y = __shfl_up(x, off, 64);
        if (lane >= off) x += y;
    }
    if (lane == 63) wtot[wid] = x;
    __syncthreads();
    if (tid == 0) { int c = 0; for (int i = 0; i < 16; ++i) { int t = wtot[i]; wtot[i] = c; c += t; } }
    __syncthreads();
    int excl = wtot[wid] + x - v;
    if (tid < NB) {
        bStart[tid] = excl;
        if (tid == NB - 1) bStart[NB] = excl + v;
    }
}

// S2c: per-(block,bucket) reservation offsets. One wave per bucket.
__global__ __launch_bounds__(256)
void s2c_scan(const int* __restrict__ H, const int* __restrict__ bStart,
              int* __restrict__ O, int NB, int nblk) {
    int wv = (blockIdx.x * 256 + threadIdx.x) >> 6;
    int lane = threadIdx.x & 63;
    if (wv >= NB) return;
    int run = bStart[wv];
    for (int k0 = 0; k0 < nblk; k0 += 64) {
        int k = k0 + lane;
        int h = (k < nblk) ? H[(long)k * NB + wv] : 0;
        int x = h;
        for (int off = 1; off < 64; off <<= 1) {
            int y = __shfl_up(x, off, 64);
            if (lane >= off) x += y;
        }
        if (k < nblk) O[(long)k * NB + wv] = run + (x - h);
        run += __shfl(x, 63, 64);
    }
}

// S3: stable bin by coarse bucket (LDS staging, coalesced flush).
__global__ __launch_bounds__(256)
void s3_bin(const int* __restrict__ row, const int* __restrict__ col,
            const float* __restrict__ ew, const int* __restrict__ O,
            int2* __restrict__ bins, int E, int N, int NB) {
    __shared__ int cnt[NBMAX];
    __shared__ int dlt[NBMAX];
    __shared__ int2 ldata[EPB];
    __shared__ int gdst[EPB];
    __shared__ int wtot[4];
    int tid = threadIdx.x;
    int lane = tid & 63, wid = tid >> 6;
    long base = (long)blockIdx.x * EPB;
    for (int i = tid; i < NB; i += 256) cnt[i] = 0;
    __syncthreads();
    for (int r = 0; r < EPB / 256; ++r) {
        long e = base + r * 256 + tid;
        if (e < E) {
            int c = col[e];
            if ((unsigned)c < (unsigned)N) atomicAdd(&cnt[c >> 7], 1);
        }
    }
    __syncthreads();
    scan4(cnt, NB, tid, wtot);
    for (int i = tid; i < NB; i += 256)
        dlt[i] = O[(long)blockIdx.x * NB + i] - cnt[i];
    __syncthreads();
    ull ltm = (lane == 0) ? 0ULL : ((~0ULL) >> (64 - lane));
    for (int r = 0; r < EPB / 256; ++r) {
        long e = base + r * 256 + tid;
        bool valid = (e < E);
        int c = 0;
        if (valid) { c = col[e]; valid = ((unsigned)c < (unsigned)N); }
        int b = valid ? (c >> 7) : 0;
        int rw = 0; float wv = 0.f;
        if (valid) { rw = row[e]; wv = ew[e]; }
        ull vm = __ballot(valid);
        ull peers = vm;
        for (int bit = 0; bit < 10; ++bit) {
            ull s = __ballot(valid && ((b >> bit) & 1));
            peers &= ((b >> bit) & 1) ? s : ~s;
        }
        int rank = __popcll(peers & ltm);
        int cng  = __popcll(peers);
        int ldr  = __ffsll(peers) - 1;
        if (ldr < 0) ldr = 0;
        int lb = 0;
        for (int w = 0; w < 4; ++w) {
            if (wid == w && valid && rank == 0) lb = atomicAdd(&cnt[b], cng);
            __syncthreads();
        }
        int lbase = __shfl(lb, ldr, 64);
        if (valid) {
            int lpos = lbase + rank;
            if ((unsigned)lpos < (unsigned)EPB) {
                ldata[lpos] = make_int2(rw | ((c & (CPB - 1)) << 17), __float_as_int(wv));
                gdst[lpos]  = lpos + dlt[b];
            }
        }
    }
    __syncthreads();
    int lenBlock = (int)((E - base < (long)EPB) ? (E - base) : (long)EPB);
    for (int p = tid; p < lenBlock; p += 256) {
        int g = gdst[p];
        if ((unsigned)g < (unsigned)E) bins[g] = ldata[p];
    }
}

// S4: per-bucket stable counting sort by local col; flush CSC (keeps colL),
// start[], per-col in-edge-order deg sums.
__global__ __launch_bounds__(256)
void s4_sort(const int* __restrict__ bStart, int2* bins,
             int* __restrict__ start, float* __restrict__ dis,
             float* __restrict__ selfw, int E, int N) {
    __shared__ int2 ldata[CAP];
    __shared__ int hist[CPB];
    __shared__ int colStart[CPB + 1];
    __shared__ int cursor[CPB];
    __shared__ int wtot[4];
    int b = blockIdx.x;
    int tid = threadIdx.x;
    int lane = tid & 63, wid = tid >> 6;
    int segs = bStart[b], sege = bStart[b + 1];
    int len = sege - segs;
    if (len > CAP) len = CAP;
    if (tid < CPB) hist[tid] = 0;
    __syncthreads();
    for (int p = tid; p < len; p += 256)
        atomicAdd(&hist[(bins[segs + p].x >> 17) & (CPB - 1)], 1);
    __syncthreads();
    if (tid < CPB) colStart[tid] = hist[tid];
    __syncthreads();
    scan4(colStart, CPB, tid, wtot);
    if (tid == 0) colStart[CPB] = len;
    if (tid < CPB) {
        int cg = b * CPB + tid;
        if (cg < N) start[cg] = segs + colStart[tid];
        cursor[tid] = colStart[tid];
    }
    if (b == (int)gridDim.x - 1 && tid == 0) start[N] = sege;
    __syncthreads();
    int rounds = (len + 255) / 256;
    ull ltm = (lane == 0) ? 0ULL : ((~0ULL) >> (64 - lane));
    for (int r = 0; r < rounds; ++r) {
        int p = r * 256 + tid;
        bool valid = (p < len);
        int2 d = valid ? bins[segs + p] : make_int2(0, 0);
        int c = valid ? ((d.x >> 17) & (CPB - 1)) : 0;
        ull vm = __ballot(valid);
        ull peers = vm;
        for (int bit = 0; bit < 7; ++bit) {
            ull s = __ballot(valid && ((c >> bit) & 1));
            peers &= ((c >> bit) & 1) ? s : ~s;
        }
        int rank = __popcll(peers & ltm);
        int cng  = __popcll(peers);
        int ldr  = __ffsll(peers) - 1;
        if (ldr < 0) ldr = 0;
        int lb = 0;
        for (int w = 0; w < 4; ++w) {
            if (wid == w && valid && rank == 0) lb = atomicAdd(&cursor[c], cng);
            __syncthreads();
        }
        int lbase = __shfl(lb, ldr, 64);
        if (valid) {
            int lpos = lbase + rank;
            if ((unsigned)lpos < (unsigned)CAP) ldata[lpos] = d;
        }
    }
    __syncthreads();
    for (int p = tid; p < len; p += 256)
        bins[segs + p] = ldata[p];
    if (tid < CPB) {
        int cg = b * CPB + tid;
        if (cg < N) {
            int s0 = colStart[tid], e0 = colStart[tid + 1];
            float dsum = 0.f;
            for (int q = s0; q < e0; ++q)
                dsum = __fadd_rn(dsum, __int_as_float(ldata[q].y));
            dsum = __fadd_rn(dsum, 1.0f);
            dis[cg] = 1.0f / __fsqrt_rn(dsum);   // == 1/np.sqrt
            selfw[cg] = 1.0f / dsum;
        }
    }
}

// S7: edge-parallel per bucket: epack (row|colL<<17, w) -> (row, norm).
__global__ __launch_bounds__(256)
void s7_norm(const int* __restrict__ bStart, int2* __restrict__ epack,
             const float* __restrict__ dis, int E) {
    int b = blockIdx.x;
    int s = bStart[b], e = bStart[b + 1];
    int cbase = b * CPB;
    for (int p = s + threadIdx.x; p < e; p += 256) {
        int2 d = epack[p];
        int row = d.x & 0x1FFFF;
        int col = cbase + ((d.x >> 17) & (CPB - 1));
        float nm = __fmul_rn(__fmul_rn(dis[row], __int_as_float(d.y)), dis[col]);
        epack[p] = make_int2(row, __float_as_int(nm));
    }
}

// CK: chunkLo[c] = first node whose start falls in edge-bucket c (node buckets
// clamped to nch-1 so every node lands in a real chunk); chunkLo[nch] = N.
__global__ void ck_chunk(const int* __restrict__ start, int* __restrict__ chunkLo,
                         int N, int nch) {
    int i = blockIdx.x * 256 + threadIdx.x;
    if (i > N) return;
    int b = (i == N) ? nch : min(start[i] / CHK, nch - 1);
    int bprev = (i == 0) ? -1 : min(start[i - 1] / CHK, nch - 1);
    for (int c = bprev + 1; c <= b; ++c) chunkLo[c] = i;
}

// ---------------------------------------------------------------------------
// gemm0: x @ W0 (K=128 -> 16), 4 threads/node, sequential-k fmaf (bit-exact).
// ---------------------------------------------------------------------------
__global__ __launch_bounds__(256)
void gemm0(const float* __restrict__ h, const float* __restrict__ W,
           float* __restrict__ hw, int N, int K) {
    int g = blockIdx.x * 256 + threadIdx.x;
    int i = g >> 2, jq = g & 3;
    if (i >= N) return;
    const float4* hv = (const float4*)(h + (long)i * K);
    const float4* Wv = (const float4*)W;
    float4 acc = make_float4(0.f, 0.f, 0.f, 0.f);
    for (int k4 = 0; k4 < K / 4; ++k4) {
        float4 h4 = hv[k4];
        float4 w0 = Wv[(4 * k4 + 0) * 4 + jq];
        acc.x = fmaf(h4.x, w0.x, acc.x); acc.y = fmaf(h4.x, w0.y, acc.y);
        acc.z = fmaf(h4.x, w0.z, acc.z); acc.w = fmaf(h4.x, w0.w, acc.w);
        float4 w1 = Wv[(4 * k4 + 1) * 4 + jq];
        acc.x = fmaf(h4.y, w1.x, acc.x); acc.y = fmaf(h4.y, w1.y, acc.y);
        acc.z = fmaf(h4.y, w1.z, acc.z); acc.w = fmaf(h4.y, w1.w, acc.w);
        float4 w2 = Wv[(4 * k4 + 2) * 4 + jq];
        acc.x = fmaf(h4.z, w2.x, acc.x); acc.y = fmaf(h4.z, w2.y, acc.y);
        acc.z = fmaf(h4.z, w2.z, acc.z); acc.w = fmaf(h4.z, w2.w, acc.w);
        float4 w3 = Wv[(4 * k4 + 3) * 4 + jq];
        acc.x = fmaf(h4.w, w3.x, acc.x); acc.y = fmaf(h4.w, w3.y, acc.y);
        acc.z = fmaf(h4.w, w3.z, acc.z); acc.w = fmaf(h4.w, w3.w, acc.w);
    }
    ((float4*)hw)[(long)i * 4 + jq] = acc;
}

// ---------------------------------------------------------------------------
// Fused layer: phase A (order-free) gathers tmp[p]=fmul(norm,hw[row]) for a
// contiguous chunk into LDS; phase B folds per node in strict edge order from
// LDS, applies self/bias/relu, then computes the NEXT layer's gemm row via
// intra-quad shfl (k-ascending fmaf). All FP sequences match the verified
// round-2 kernels exactly.
// ---------------------------------------------------------------------------

#define GATH(t) { int tt = (t); if (tt < ntask) { \
    int p = tt >> 2; int q = tt & 3; \
    int2 d = epack[ebase + p]; \
    float nm = __int_as_float(d.y); \
    float4 gv = hwv[(long)d.x * 4 + q]; \
    tmp[p * 4 + q] = make_float4(__fmul_rn(nm, gv.x), __fmul_rn(nm, gv.y), \
                                 __fmul_rn(nm, gv.z), __fmul_rn(nm, gv.w)); } }

template <int GQ>   // GQ = FOUT/4 quarters of the fused NEXT-layer gemm
__global__ __launch_bounds__(256)
void fused_layer(const float* __restrict__ hw, const int2* __restrict__ epack,
                 const int* __restrict__ start, const int* __restrict__ chunkLo,
                 const float* __restrict__ selfw, const float* __restrict__ bias,
                 const float* __restrict__ W, float* __restrict__ hwout, int N) {
    __shared__ float4 tmp[SPAN * 4];
    int c = blockIdx.x;
    int lo = chunkLo[c], hi = chunkLo[c + 1];
    if (lo >= hi) return;
    int ebase = start[lo];
    int span = start[hi] - ebase;
    if (span > SPAN) span = SPAN;          // impossible-case guard
    int tid = threadIdx.x;
    const float4* hwv = (const float4*)hw;
    int ntask = span * 4;
    for (int t = tid; t < ntask; t += 1024) {
        GATH(t) GATH(t + 256) GATH(t + 512) GATH(t + 768)
    }
    __syncthreads();
    const float4* Wv = (const float4*)W;
    int fq = tid & 3;
    int lbase = (tid & 63) & ~3;
    for (int n = lo + (tid >> 2); n < hi; n += 64) {
        int s = start[n] - ebase, e = start[n + 1] - ebase;
        if (e > span) e = span;
        float4 acc = make_float4(0.f, 0.f, 0.f, 0.f);
        for (int p = s; p < e; ++p) {
            float4 v = tmp[p * 4 + fq];
            acc.x = __fadd_rn(acc.x, v.x);
            acc.y = __fadd_rn(acc.y, v.y);
            acc.z = __fadd_rn(acc.z, v.z);
            acc.w = __fadd_rn(acc.w, v.w);
        }
        float sw = selfw[n];
        float4 sv = hwv[(long)n * 4 + fq];
        acc.x = __fadd_rn(acc.x, __fmul_rn(sw, sv.x));
        acc.y = __fadd_rn(acc.y, __fmul_rn(sw, sv.y));
        acc.z = __fadd_rn(acc.z, __fmul_rn(sw, sv.z));
        acc.w = __fadd_rn(acc.w, __fmul_rn(sw, sv.w));
        float4 bv = ((const float4*)bias)[fq];
        acc.x = fmaxf(__fadd_rn(acc.x, bv.x), 0.f);
        acc.y = fmaxf(__fadd_rn(acc.y, bv.y), 0.f);
        acc.z = fmaxf(__fadd_rn(acc.z, bv.z), 0.f);
        acc.w = fmaxf(__fadd_rn(acc.w, bv.w), 0.f);
        // fused gemm: out_j = sum_k h[k]*W[k][j], k ascending (bit-exact order)
        float4 out = make_float4(0.f, 0.f, 0.f, 0.f);
#pragma unroll
        for (int q = 0; q < 4; ++q) {
            int src = lbase + q;
            float4 hh;
            hh.x = __shfl(acc.x, src, 64);
            hh.y = __shfl(acc.y, src, 64);
            hh.z = __shfl(acc.z, src, 64);
            hh.w = __shfl(acc.w, src, 64);
            if (fq < GQ) {
                float4 w0 = Wv[(4 * q + 0) * GQ + fq];
                out.x = fmaf(hh.x, w0.x, out.x); out.y = fmaf(hh.x, w0.y, out.y);
                out.z = fmaf(hh.x, w0.z, out.z); out.w = fmaf(hh.x, w0.w, out.w);
                float4 w1 = Wv[(4 * q + 1) * GQ + fq];
                out.x = fmaf(hh.y, w1.x, out.x); out.y = fmaf(hh.y, w1.y, out.y);
                out.z = fmaf(hh.y, w1.z, out.z); out.w = fmaf(hh.y, w1.w, out.w);
                float4 w2 = Wv[(4 * q + 2) * GQ + fq];
                out.x = fmaf(hh.z, w2.x, out.x); out.y = fmaf(hh.z, w2.y, out.y);
                out.z = fmaf(hh.z, w2.z, out.z); out.w = fmaf(hh.z, w2.w, out.w);
                float4 w3 = Wv[(4 * q + 3) * GQ + fq];
                out.x = fmaf(hh.w, w3.x, out.x); out.y = fmaf(hh.w, w3.y, out.y);
                out.z = fmaf(hh.w, w3.z, out.z); out.w = fmaf(hh.w, w3.w, out.w);
            }
        }
        if (fq < GQ) ((float4*)hwout)[(long)n * GQ + fq] = out;
    }
}

// Final agg (F=12): same phase-split, no fused gemm; writes d_out directly.
#define GATH3(t) { int tt = (t); if (tt < ntask) { \
    int p = tt / 3; int q = tt - p * 3; \
    int2 d = epack[ebase + p]; \
    float nm = __int_as_float(d.y); \
    float4 gv = hwv[(long)d.x * 3 + q]; \
    tmp[p * 3 + q] = make_float4(__fmul_rn(nm, gv.x), __fmul_rn(nm, gv.y), \
                                 __fmul_rn(nm, gv.z), __fmul_rn(nm, gv.w)); } }

__global__ __launch_bounds__(256)
void agg_final(const float* __restrict__ hw, const int2* __restrict__ epack,
               const int* __restrict__ start, const int* __restrict__ chunkLo,
               const float* __restrict__ selfw, const float* __restrict__ bias,
               float* __restrict__ outp, int N) {
    __shared__ float4 tmp[SPAN * 3];
    int c = blockIdx.x;
    int lo = chunkLo[c], hi = chunkLo[c + 1];
    if (lo >= hi) return;
    int ebase = start[lo];
    int span = start[hi] - ebase;
    if (span > SPAN) span = SPAN;
    int tid = threadIdx.x;
    const float4* hwv = (const float4*)hw;
    int ntask = span * 3;
    for (int t = tid; t < ntask; t += 1024) {
        GATH3(t) GATH3(t + 256) GATH3(t + 512) GATH3(t + 768)
    }
    __syncthreads();
    int fq = tid & 3;
    for (int n = lo + (tid >> 2); n < hi; n += 64) {
        if (fq >= 3) continue;
        int s = start[n] - ebase, e = start[n + 1] - ebase;
        if (e > span) e = span;
        float4 acc = make_float4(0.f, 0.f, 0.f, 0.f);
        for (int p = s; p < e; ++p) {
            float4 v = tmp[p * 3 + fq];
            acc.x = __fadd_rn(acc.x, v.x);
            acc.y = __fadd_rn(acc.y, v.y);
            acc.z = __fadd_rn(acc.z, v.z);
            acc.w = __fadd_rn(acc.w, v.w);
        }
        float sw = selfw[n];
        float4 sv = hwv[(long)n * 3 + fq];
        acc.x = __fadd_rn(acc.x, __fmul_rn(sw, sv.x));
        acc.y = __fadd_rn(acc.y, __fmul_rn(sw, sv.y));
        acc.z = __fadd_rn(acc.z, __fmul_rn(sw, sv.z));
        acc.w = __fadd_rn(acc.w, __fmul_rn(sw, sv.w));
        float4 bv = ((const float4*)bias)[fq];
        acc.x = fmaxf(__fadd_rn(acc.x, bv.x), 0.f);
        acc.y = fmaxf(__fadd_rn(acc.y, bv.y), 0.f);
        acc.z = fmaxf(__fadd_rn(acc.z, bv.z), 0.f);
        acc.w = fmaxf(__fadd_rn(acc.w, bv.w), 0.f);
        ((float4*)outp)[(long)n * 3 + fq] = acc;
    }
}

// ---------------------------------------------------------------------------

extern "C" void kernel_launch(void* const* d_in, const int* in_sizes, int n_in,
                              void* d_out, int out_size, void* d_ws, size_t ws_size,
                              hipStream_t stream) {
    const float* x      = (const float*)d_in[0];
    const int*   ei     = (const int*)d_in[1];
    const float* ew     = (const float*)d_in[2];
    const float* W0     = (const float*)d_in[3];
    const float* b0     = (const float*)d_in[4];
    const float* Wmid   = (const float*)d_in[5];
    const float* bmid   = (const float*)d_in[6];
    const float* Wlast  = (const float*)d_in[7];
    const float* blast  = (const float*)d_in[8];

    const int N = in_sizes[0] / DIN;              // 100000
    const int E = in_sizes[2];                    // 3200000
    const int* row32 = ei;
    const int* col32 = ei + E;
    const int nblk = (E + EPB - 1) / EPB;         // 782
    const int NB   = (N + CPB - 1) / CPB;         // 782
    const int nch  = (E + CHK - 1) / CHK;         // 12500

    char* w = (char*)d_ws;
    size_t off = 0;
    auto alloc = [&](size_t bytes) -> void* {
        void* p = w + off;
        off = (off + bytes + 255) & ~(size_t)255;
        return p;
    };
    int*  T       = (int*)alloc((size_t)NB * 4);
    int*  bStart  = (int*)alloc((size_t)(NB + 1) * 4);
    int*  H       = (int*)alloc((size_t)nblk * NB * 4);
    int*  O       = (int*)alloc((size_t)nblk * NB * 4);
    int*  start   = (int*)alloc((size_t)(N + 1) * 4);
    float* dis    = (float*)alloc((size_t)N * 4);
    float* selfw  = (float*)alloc((size_t)N * 4);
    int*  chunkLo = (int*)alloc((size_t)(nch + 1) * 4);
    int2* bins    = (int2*)alloc(((size_t)E + 8) * 8);
    float* hwA    = (float*)alloc((size_t)N * HID * 4);
    float* hwB    = (float*)alloc((size_t)N * HID * 4);
    (void)ws_size;

    hipMemsetAsync(T, 0, (size_t)NB * 4, stream);

    s1_hist<<<nblk, 256, 0, stream>>>(col32, H, T, E, N, NB);
    s2b_scan<<<1, 1024, 0, stream>>>(T, bStart, NB);
    s2c_scan<<<(NB * 64 + 255) / 256, 256, 0, stream>>>(H, bStart, O, NB, nblk);
    s3_bin<<<nblk, 256, 0, stream>>>(row32, col32, ew, O, bins, E, N, NB);
    s4_sort<<<NB, 256, 0, stream>>>(bStart, bins, start, dis, selfw, E, N);
    ck_chunk<<<(N + 1 + 255) / 256, 256, 0, stream>>>(start, chunkLo, N, nch);
    s7_norm<<<NB, 256, 0, stream>>>(bStart, bins, dis, E);
    int2* epack = bins;

    int gridN4 = (N * 4 + 255) / 256;
    gemm0<<<gridN4, 256, 0, stream>>>(x, W0, hwA, N, DIN);

    float* bufs[2] = {hwA, hwB};
    // fused_l = agg_l (bias_l) + gemm_{l+1}  for l = 0..11
    for (int l = 0; l < 11; ++l) {
        const float* bias = (l == 0) ? b0 : bmid + (size_t)(l - 1) * HID;
        const float* Wn   = Wmid + (size_t)l * HID * HID;
        fused_layer<4><<<nch, 256, 0, stream>>>(bufs[l & 1], epack, start, chunkLo,
                                                selfw, bias, Wn, bufs[(l + 1) & 1], N);
    }
    // l = 11: bias = bmid[10], next gemm = Wlast (16 -> 12)
    fused_layer<3><<<nch, 256, 0, stream>>>(bufs[1], epack, start, chunkLo,
                                            selfw, bmid + (size_t)10 * HID, Wlast,
                                            bufs[0], N);
    // final agg over 12-wide hw, bias blast -> d_out
    agg_final<<<nch, 256, 0, stream>>>(bufs[0], epack, start, chunkLo,
                                       selfw, blast, (float*)d_out, N);
}

// Round 10
// 1049.680 us; speedup vs baseline: 1.3158x; 1.3158x over previous
//
#include <hip/hip_runtime.h>
#include <math.h>

#define DIN 128
#define HID 16
#define DOUT 12
#define NMID 11

#define CPB 128        // cols per bucket (col >> 7)
#define NBMAX 800      // max coarse buckets (runtime 782)
#define EPB 4096       // edges per binning block
#define CAP 5120       // max edges per bucket in s4 LDS
#define NPB 1024       // nodes per perm-build block

typedef unsigned long long ull;

// exclusive scan in place over arr[0..L), 256 threads, L <= 1024
__device__ __forceinline__ void scan4(int* arr, int L, int tid, int* wtot) {
    int lane = tid & 63, wid = tid >> 6;
    int v[4]; int s = 0;
#pragma unroll
    for (int j = 0; j < 4; ++j) {
        int idx = tid * 4 + j;
        int t = (idx < L) ? arr[idx] : 0;
        v[j] = s; s += t;
    }
    int x = s;
    for (int off = 1; off < 64; off <<= 1) {
        int y = __shfl_up(x, off, 64);
        if (lane >= off) x += y;
    }
    if (lane == 63) wtot[wid] = x;
    __syncthreads();
    if (tid == 0) { int c = 0; for (int i = 0; i < 4; ++i) { int t = wtot[i]; wtot[i] = c; c += t; } }
    __syncthreads();
    int b0 = wtot[wid] + (x - s);
#pragma unroll
    for (int j = 0; j < 4; ++j) {
        int idx = tid * 4 + j;
        if (idx < L) arr[idx] = b0 + v[j];
    }
    __syncthreads();
}

// S1: per-block coarse histogram + global bucket totals.
__global__ __launch_bounds__(256)
void s1_hist(const int* __restrict__ col, int* __restrict__ H, int* __restrict__ T,
             int E, int N, int NB) {
    __shared__ int hist[NBMAX];
    int tid = threadIdx.x;
    for (int i = tid; i < NB; i += 256) hist[i] = 0;
    __syncthreads();
    long base = (long)blockIdx.x * EPB;
    for (int r = 0; r < EPB / 256; ++r) {
        long e = base + r * 256 + tid;
        if (e < E) {
            int c = col[e];
            if ((unsigned)c < (unsigned)N) atomicAdd(&hist[c >> 7], 1);
        }
    }
    __syncthreads();
    for (int i = tid; i < NB; i += 256) {
        int h = hist[i];
        H[(long)blockIdx.x * NB + i] = h;
        if (h) atomicAdd(&T[i], h);
    }
}

// S2b: exclusive scan of bucket totals -> bStart[0..NB], single block.
__global__ __launch_bounds__(1024)
void s2b_scan(const int* __restrict__ T, int* __restrict__ bStart, int NB) {
    __shared__ int wtot[16];
    int tid = threadIdx.x, lane = tid & 63, wid = tid >> 6;
    int v = (tid < NB) ? T[tid] : 0;
    int x = v;
    for (int off = 1; off < 64; off <<= 1) {
        int y = __shfl_up(x, off, 64);
        if (lane >= off) x += y;
    }
    if (lane == 63) wtot[wid] = x;
    __syncthreads();
    if (tid == 0) { int c = 0; for (int i = 0; i < 16; ++i) { int t = wtot[i]; wtot[i] = c; c += t; } }
    __syncthreads();
    int excl = wtot[wid] + x - v;
    if (tid < NB) {
        bStart[tid] = excl;
        if (tid == NB - 1) bStart[NB] = excl + v;
    }
}

// S2c: per-(block,bucket) reservation offsets. One wave per bucket.
__global__ __launch_bounds__(256)
void s2c_scan(const int* __restrict__ H, const int* __restrict__ bStart,
              int* __restrict__ O, int NB, int nblk) {
    int wv = (blockIdx.x * 256 + threadIdx.x) >> 6;
    int lane = threadIdx.x & 63;
    if (wv >= NB) return;
    int run = bStart[wv];
    for (int k0 = 0; k0 < nblk; k0 += 64) {
        int k = k0 + lane;
        int h = (k < nblk) ? H[(long)k * NB + wv] : 0;
        int x = h;
        for (int off = 1; off < 64; off <<= 1) {
            int y = __shfl_up(x, off, 64);
            if (lane >= off) x += y;
        }
        if (k < nblk) O[(long)k * NB + wv] = run + (x - h);
        run += __shfl(x, 63, 64);
    }
}

// S3: stable bin by coarse bucket (LDS staging, coalesced flush).
__global__ __launch_bounds__(256)
void s3_bin(const int* __restrict__ row, const int* __restrict__ col,
            const float* __restrict__ ew, const int* __restrict__ O,
            int2* __restrict__ bins, int E, int N, int NB) {
    __shared__ int cnt[NBMAX];
    __shared__ int dlt[NBMAX];
    __shared__ int2 ldata[EPB];
    __shared__ int gdst[EPB];
    __shared__ int wtot[4];
    int tid = threadIdx.x;
    int lane = tid & 63, wid = tid >> 6;
    long base = (long)blockIdx.x * EPB;
    for (int i = tid; i < NB; i += 256) cnt[i] = 0;
    __syncthreads();
    for (int r = 0; r < EPB / 256; ++r) {
        long e = base + r * 256 + tid;
        if (e < E) {
            int c = col[e];
            if ((unsigned)c < (unsigned)N) atomicAdd(&cnt[c >> 7], 1);
        }
    }
    __syncthreads();
    scan4(cnt, NB, tid, wtot);
    for (int i = tid; i < NB; i += 256)
        dlt[i] = O[(long)blockIdx.x * NB + i] - cnt[i];
    __syncthreads();
    ull ltm = (lane == 0) ? 0ULL : ((~0ULL) >> (64 - lane));
    for (int r = 0; r < EPB / 256; ++r) {
        long e = base + r * 256 + tid;
        bool valid = (e < E);
        int c = 0;
        if (valid) { c = col[e]; valid = ((unsigned)c < (unsigned)N); }
        int b = valid ? (c >> 7) : 0;
        int rw = 0; float wv = 0.f;
        if (valid) { rw = row[e]; wv = ew[e]; }
        ull vm = __ballot(valid);
        ull peers = vm;
        for (int bit = 0; bit < 10; ++bit) {
            ull s = __ballot(valid && ((b >> bit) & 1));
            peers &= ((b >> bit) & 1) ? s : ~s;
        }
        int rank = __popcll(peers & ltm);
        int cng  = __popcll(peers);
        int ldr  = __ffsll(peers) - 1;
        if (ldr < 0) ldr = 0;
        int lb = 0;
        for (int w = 0; w < 4; ++w) {
            if (wid == w && valid && rank == 0) lb = atomicAdd(&cnt[b], cng);
            __syncthreads();
        }
        int lbase = __shfl(lb, ldr, 64);
        if (valid) {
            int lpos = lbase + rank;
            if ((unsigned)lpos < (unsigned)EPB) {
                ldata[lpos] = make_int2(rw | ((c & (CPB - 1)) << 17), __float_as_int(wv));
                gdst[lpos]  = lpos + dlt[b];
            }
        }
    }
    __syncthreads();
    int lenBlock = (int)((E - base < (long)EPB) ? (E - base) : (long)EPB);
    for (int p = tid; p < lenBlock; p += 256) {
        int g = gdst[p];
        if ((unsigned)g < (unsigned)E) bins[g] = ldata[p];
    }
}

// S4: per-bucket stable counting sort by local col; flush CSC (keeps colL),
// start[], per-col in-edge-order deg sums.
__global__ __launch_bounds__(256)
void s4_sort(const int* __restrict__ bStart, int2* bins,
             int* __restrict__ start, float* __restrict__ dis,
             float* __restrict__ selfw, int E, int N) {
    __shared__ int2 ldata[CAP];
    __shared__ int hist[CPB];
    __shared__ int colStart[CPB + 1];
    __shared__ int cursor[CPB];
    __shared__ int wtot[4];
    int b = blockIdx.x;
    int tid = threadIdx.x;
    int lane = tid & 63, wid = tid >> 6;
    int segs = bStart[b], sege = bStart[b + 1];
    int len = sege - segs;
    if (len > CAP) len = CAP;
    if (tid < CPB) hist[tid] = 0;
    __syncthreads();
    for (int p = tid; p < len; p += 256)
        atomicAdd(&hist[(bins[segs + p].x >> 17) & (CPB - 1)], 1);
    __syncthreads();
    if (tid < CPB) colStart[tid] = hist[tid];
    __syncthreads();
    scan4(colStart, CPB, tid, wtot);
    if (tid == 0) colStart[CPB] = len;
    if (tid < CPB) {
        int cg = b * CPB + tid;
        if (cg < N) start[cg] = segs + colStart[tid];
        cursor[tid] = colStart[tid];
    }
    if (b == (int)gridDim.x - 1 && tid == 0) start[N] = sege;
    __syncthreads();
    int rounds = (len + 255) / 256;
    ull ltm = (lane == 0) ? 0ULL : ((~0ULL) >> (64 - lane));
    for (int r = 0; r < rounds; ++r) {
        int p = r * 256 + tid;
        bool valid = (p < len);
        int2 d = valid ? bins[segs + p] : make_int2(0, 0);
        int c = valid ? ((d.x >> 17) & (CPB - 1)) : 0;
        ull vm = __ballot(valid);
        ull peers = vm;
        for (int bit = 0; bit < 7; ++bit) {
            ull s = __ballot(valid && ((c >> bit) & 1));
            peers &= ((c >> bit) & 1) ? s : ~s;
        }
        int rank = __popcll(peers & ltm);
        int cng  = __popcll(peers);
        int ldr  = __ffsll(peers) - 1;
        if (ldr < 0) ldr = 0;
        int lb = 0;
        for (int w = 0; w < 4; ++w) {
            if (wid == w && valid && rank == 0) lb = atomicAdd(&cursor[c], cng);
            __syncthreads();
        }
        int lbase = __shfl(lb, ldr, 64);
        if (valid) {
            int lpos = lbase + rank;
            if ((unsigned)lpos < (unsigned)CAP) ldata[lpos] = d;
        }
    }
    __syncthreads();
    for (int p = tid; p < len; p += 256)
        bins[segs + p] = ldata[p];
    if (tid < CPB) {
        int cg = b * CPB + tid;
        if (cg < N) {
            int s0 = colStart[tid], e0 = colStart[tid + 1];
            float dsum = 0.f;
            for (int q = s0; q < e0; ++q)
                dsum = __fadd_rn(dsum, __int_as_float(ldata[q].y));
            dsum = __fadd_rn(dsum, 1.0f);
            dis[cg] = 1.0f / __fsqrt_rn(dsum);   // == 1/np.sqrt
            selfw[cg] = 1.0f / dsum;
        }
    }
}

// ---------------------------------------------------------------------------
// Degree-sorted node permutation (scan-built).
// ---------------------------------------------------------------------------

__device__ __forceinline__ int deg_bin(const int* start, int i) {
    int d = start[i + 1] - start[i];
    return 255 - (d > 255 ? 255 : d);
}

__global__ __launch_bounds__(256)
void pd1_hist(const int* __restrict__ start, int* __restrict__ HD, int N) {
    __shared__ int hist[256];
    int tid = threadIdx.x;
    hist[tid] = 0;
    __syncthreads();
    int base = blockIdx.x * NPB;
    for (int r = 0; r < NPB / 256; ++r) {
        int i = base + r * 256 + tid;
        if (i < N) atomicAdd(&hist[deg_bin(start, i)], 1);
    }
    __syncthreads();
    HD[blockIdx.x * 256 + tid] = hist[tid];
}

__global__ __launch_bounds__(256)
void pd2a_scan(const int* __restrict__ HD, int* __restrict__ binStart, int nbk) {
    __shared__ int arr[256];
    __shared__ int wtot[4];
    int tid = threadIdx.x;
    int tot = 0;
    for (int k = 0; k < nbk; ++k) tot += HD[k * 256 + tid];
    arr[tid] = tot;
    __syncthreads();
    scan4(arr, 256, tid, wtot);
    binStart[tid] = arr[tid];
}

__global__ __launch_bounds__(256)
void pd2b_off(const int* __restrict__ HD, const int* __restrict__ binStart,
              int* __restrict__ OD, int nbk) {
    int wv = (blockIdx.x * 256 + threadIdx.x) >> 6;
    int lane = threadIdx.x & 63;
    if (wv >= 256) return;
    int run = binStart[wv];
    for (int k0 = 0; k0 < nbk; k0 += 64) {
        int k = k0 + lane;
        int h = (k < nbk) ? HD[k * 256 + wv] : 0;
        int x = h;
        for (int off = 1; off < 64; off <<= 1) {
            int y = __shfl_up(x, off, 64);
            if (lane >= off) x += y;
        }
        if (k < nbk) OD[k * 256 + wv] = run + (x - h);
        run += __shfl(x, 63, 64);
    }
}

__global__ __launch_bounds__(256)
void pd3_fill(const int* __restrict__ start, const int* __restrict__ OD,
              int* __restrict__ perm, int N) {
    __shared__ int cnt[256];
    __shared__ int dlt[256];
    __shared__ int wtot[4];
    int tid = threadIdx.x;
    int lane = tid & 63, wid = tid >> 6;
    int base = blockIdx.x * NPB;
    cnt[tid] = 0;
    __syncthreads();
    for (int r = 0; r < NPB / 256; ++r) {
        int i = base + r * 256 + tid;
        if (i < N) atomicAdd(&cnt[deg_bin(start, i)], 1);
    }
    __syncthreads();
    scan4(cnt, 256, tid, wtot);
    dlt[tid] = OD[blockIdx.x * 256 + tid] - cnt[tid];
    __syncthreads();
    ull ltm = (lane == 0) ? 0ULL : ((~0ULL) >> (64 - lane));
    for (int r = 0; r < NPB / 256; ++r) {
        int i = base + r * 256 + tid;
        bool valid = (i < N);
        int b = valid ? deg_bin(start, i) : 0;
        ull peers = __ballot(valid);
        for (int bit = 0; bit < 8; ++bit) {
            ull s = __ballot(valid && ((b >> bit) & 1));
            peers &= ((b >> bit) & 1) ? s : ~s;
        }
        int rank = __popcll(peers & ltm);
        int cng  = __popcll(peers);
        int ldr  = __ffsll(peers) - 1;
        if (ldr < 0) ldr = 0;
        int lb = 0;
        for (int w = 0; w < 4; ++w) {
            if (wid == w && valid && rank == 0) lb = atomicAdd(&cnt[b], cng);
            __syncthreads();
        }
        int lbase = __shfl(lb, ldr, 64);
        if (valid) {
            int gpos = lbase + rank + dlt[b];
            if ((unsigned)gpos < (unsigned)N) perm[gpos] = i;
        }
    }
}

__global__ void pd4_inv(const int* __restrict__ perm, int* __restrict__ iperm, int N) {
    int j = blockIdx.x * 256 + threadIdx.x;
    if (j < N) {
        int node = perm[j];
        if ((unsigned)node < (unsigned)N) iperm[node] = j;
    }
}

// nodepack[j] = {node, start[node], end[node], selfw[node]}
__global__ void p4_pack(const int* __restrict__ perm, const int* __restrict__ start,
                        const float* __restrict__ selfw, int4* __restrict__ nodepack,
                        int N) {
    int j = blockIdx.x * 256 + threadIdx.x;
    if (j < N) {
        int node = perm[j];
        nodepack[j] = make_int4(node, start[node], start[node + 1],
                                __float_as_int(selfw[node]));
    }
}

// S7: edge-parallel per bucket: (row|colL<<17, w) -> (iperm[row], norm).
// Pads 8 zero entries past E (agg's unguarded chunk prefetch).
__global__ __launch_bounds__(256)
void s7_norm(const int* __restrict__ bStart, int2* __restrict__ epack,
             const float* __restrict__ dis, const int* __restrict__ iperm, int E) {
    int b = blockIdx.x;
    if (b == 0 && threadIdx.x < 8) epack[E + threadIdx.x] = make_int2(0, 0);
    int s = bStart[b], e = bStart[b + 1];
    int cbase = b * CPB;
    for (int p = s + threadIdx.x; p < e; p += 256) {
        int2 d = epack[p];
        int row = d.x & 0x1FFFF;
        int col = cbase + ((d.x >> 17) & (CPB - 1));
        float nm = __fmul_rn(__fmul_rn(dis[row], __int_as_float(d.y)), dis[col]);
        epack[p] = make_int2(iperm[row], __float_as_int(nm));
    }
}

// ---------------------------------------------------------------------------
// gemm0: hw0[j] = x[perm[j]] @ W0 (K=128 -> 16). Sequential-k fmaf.
// ---------------------------------------------------------------------------
__global__ __launch_bounds__(256)
void gemm0(const float* __restrict__ h, const float* __restrict__ W,
           float* __restrict__ hw, const int* __restrict__ perm, int N, int K) {
    int g = blockIdx.x * 256 + threadIdx.x;
    int i = g >> 2, jq = g & 3;
    if (i >= N) return;
    int row = perm[i];
    const float4* hv = (const float4*)(h + (long)row * K);
    const float4* Wv = (const float4*)W;
    float4 acc = make_float4(0.f, 0.f, 0.f, 0.f);
    for (int k4 = 0; k4 < K / 4; ++k4) {
        float4 h4 = hv[k4];
        float4 w0 = Wv[(4 * k4 + 0) * 4 + jq];
        acc.x = fmaf(h4.x, w0.x, acc.x); acc.y = fmaf(h4.x, w0.y, acc.y);
        acc.z = fmaf(h4.x, w0.z, acc.z); acc.w = fmaf(h4.x, w0.w, acc.w);
        float4 w1 = Wv[(4 * k4 + 1) * 4 + jq];
        acc.x = fmaf(h4.y, w1.x, acc.x); acc.y = fmaf(h4.y, w1.y, acc.y);
        acc.z = fmaf(h4.y, w1.z, acc.z); acc.w = fmaf(h4.y, w1.w, acc.w);
        float4 w2 = Wv[(4 * k4 + 2) * 4 + jq];
        acc.x = fmaf(h4.z, w2.x, acc.x); acc.y = fmaf(h4.z, w2.y, acc.y);
        acc.z = fmaf(h4.z, w2.z, acc.z); acc.w = fmaf(h4.z, w2.w, acc.w);
        float4 w3 = Wv[(4 * k4 + 3) * 4 + jq];
        acc.x = fmaf(h4.w, w3.x, acc.x); acc.y = fmaf(h4.w, w3.y, acc.y);
        acc.z = fmaf(h4.w, w3.z, acc.z); acc.w = fmaf(h4.w, w3.w, acc.w);
    }
    ((float4*)hw)[(long)i * 4 + jq] = acc;
}

#define FOLD(dd, gg) { float nm = __int_as_float(dd.y); \
    acc.x = __fadd_rn(acc.x, __fmul_rn(nm, gg.x)); \
    acc.y = __fadd_rn(acc.y, __fmul_rn(nm, gg.y)); \
    acc.z = __fadd_rn(acc.z, __fmul_rn(nm, gg.z)); \
    acc.w = __fadd_rn(acc.w, __fmul_rn(nm, gg.w)); }

// ---------------------------------------------------------------------------
// agg_fused: R8's 4-deep pipelined agg (F=16 input) + fused NEXT-layer gemm
// epilogue (quad shfl, k-ascending fmaf — bit-exact, proven R9).
// GQ = output width / 4 (4 for 16-wide Wmid, 3 for 12-wide Wlast).
// ---------------------------------------------------------------------------
template <int GQ>
__global__ __launch_bounds__(256)
void agg_fused(const float* __restrict__ hw, const int2* __restrict__ epack,
               const int4* __restrict__ nodepack, const float* __restrict__ bias,
               const float* __restrict__ W, float* __restrict__ hwout, int N) {
    int g = blockIdx.x * 256 + threadIdx.x;
    int j = g >> 2, fq = g & 3;
    if (j >= N) return;
    const float4* hwv = (const float4*)hw;
    int4 np = nodepack[j];
    int s = np.y, e = np.z;
    float sw = __int_as_float(np.w);
    float4 acc = make_float4(0.f, 0.f, 0.f, 0.f);

    int2 d0 = epack[s],     d1 = epack[s + 1],
         d2 = epack[s + 2], d3 = epack[s + 3];
    float4 g0 = hwv[d0.x * 4 + fq], g1 = hwv[d1.x * 4 + fq],
           g2 = hwv[d2.x * 4 + fq], g3 = hwv[d3.x * 4 + fq];
    int p = s;
    int nfull = (e - s) >> 2;
    for (int c = 0; c < nfull; ++c) {
        int pn = p + 4;
        int2 e0 = epack[pn],     e1 = epack[pn + 1],
             e2 = epack[pn + 2], e3 = epack[pn + 3];
        float4 h0 = hwv[e0.x * 4 + fq], h1 = hwv[e1.x * 4 + fq],
               h2 = hwv[e2.x * 4 + fq], h3 = hwv[e3.x * 4 + fq];
        FOLD(d0, g0) FOLD(d1, g1) FOLD(d2, g2) FOLD(d3, g3)
        d0 = e0; d1 = e1; d2 = e2; d3 = e3;
        g0 = h0; g1 = h1; g2 = h2; g3 = h3;
        p = pn;
    }
    int rem = e - p;
    if (rem > 0) FOLD(d0, g0)
    if (rem > 1) FOLD(d1, g1)
    if (rem > 2) FOLD(d2, g2)

    float4 sv = hwv[(long)j * 4 + fq];   // self row: linear in perm space
    acc.x = __fadd_rn(acc.x, __fmul_rn(sw, sv.x));
    acc.y = __fadd_rn(acc.y, __fmul_rn(sw, sv.y));
    acc.z = __fadd_rn(acc.z, __fmul_rn(sw, sv.z));
    acc.w = __fadd_rn(acc.w, __fmul_rn(sw, sv.w));
    float4 bv = ((const float4*)bias)[fq];
    acc.x = fmaxf(__fadd_rn(acc.x, bv.x), 0.f);
    acc.y = fmaxf(__fadd_rn(acc.y, bv.y), 0.f);
    acc.z = fmaxf(__fadd_rn(acc.z, bv.z), 0.f);
    acc.w = fmaxf(__fadd_rn(acc.w, bv.w), 0.f);

    // fused gemm: out_j = sum_k h[k]*W[k][j], k ascending (bit-exact order)
    const float4* Wv = (const float4*)W;
    int lbase = (threadIdx.x & 63) & ~3;
    float4 out = make_float4(0.f, 0.f, 0.f, 0.f);
#pragma unroll
    for (int q = 0; q < 4; ++q) {
        int src = lbase + q;
        float4 hh;
        hh.x = __shfl(acc.x, src, 64);
        hh.y = __shfl(acc.y, src, 64);
        hh.z = __shfl(acc.z, src, 64);
        hh.w = __shfl(acc.w, src, 64);
        if (fq < GQ) {
            float4 w0 = Wv[(4 * q + 0) * GQ + fq];
            out.x = fmaf(hh.x, w0.x, out.x); out.y = fmaf(hh.x, w0.y, out.y);
            out.z = fmaf(hh.x, w0.z, out.z); out.w = fmaf(hh.x, w0.w, out.w);
            float4 w1 = Wv[(4 * q + 1) * GQ + fq];
            out.x = fmaf(hh.y, w1.x, out.x); out.y = fmaf(hh.y, w1.y, out.y);
            out.z = fmaf(hh.y, w1.z, out.z); out.w = fmaf(hh.y, w1.w, out.w);
            float4 w2 = Wv[(4 * q + 2) * GQ + fq];
            out.x = fmaf(hh.z, w2.x, out.x); out.y = fmaf(hh.z, w2.y, out.y);
            out.z = fmaf(hh.z, w2.z, out.z); out.w = fmaf(hh.z, w2.w, out.w);
            float4 w3 = Wv[(4 * q + 3) * GQ + fq];
            out.x = fmaf(hh.w, w3.x, out.x); out.y = fmaf(hh.w, w3.y, out.y);
            out.z = fmaf(hh.w, w3.z, out.z); out.w = fmaf(hh.w, w3.w, out.w);
        }
    }
    if (fq < GQ) ((float4*)hwout)[(long)j * GQ + fq] = out;
}

// agg_last: F=12 input, no gemm; scatters to d_out by original node id.
__global__ __launch_bounds__(256)
void agg_last(const float* __restrict__ hw, const int2* __restrict__ epack,
              const int4* __restrict__ nodepack, const float* __restrict__ bias,
              float* __restrict__ out, int N) {
    int g = blockIdx.x * 256 + threadIdx.x;
    int j = g >> 2, fq = g & 3;
    if (j >= N || fq >= 3) return;
    const float4* hwv = (const float4*)hw;
    int4 np = nodepack[j];
    int s = np.y, e = np.z;
    float sw = __int_as_float(np.w);
    float4 acc = make_float4(0.f, 0.f, 0.f, 0.f);

    int2 d0 = epack[s],     d1 = epack[s + 1],
         d2 = epack[s + 2], d3 = epack[s + 3];
    float4 g0 = hwv[d0.x * 3 + fq], g1 = hwv[d1.x * 3 + fq],
           g2 = hwv[d2.x * 3 + fq], g3 = hwv[d3.x * 3 + fq];
    int p = s;
    int nfull = (e - s) >> 2;
    for (int c = 0; c < nfull; ++c) {
        int pn = p + 4;
        int2 e0 = epack[pn],     e1 = epack[pn + 1],
             e2 = epack[pn + 2], e3 = epack[pn + 3];
        float4 h0 = hwv[e0.x * 3 + fq], h1 = hwv[e1.x * 3 + fq],
               h2 = hwv[e2.x * 3 + fq], h3 = hwv[e3.x * 3 + fq];
        FOLD(d0, g0) FOLD(d1, g1) FOLD(d2, g2) FOLD(d3, g3)
        d0 = e0; d1 = e1; d2 = e2; d3 = e3;
        g0 = h0; g1 = h1; g2 = h2; g3 = h3;
        p = pn;
    }
    int rem = e - p;
    if (rem > 0) FOLD(d0, g0)
    if (rem > 1) FOLD(d1, g1)
    if (rem > 2) FOLD(d2, g2)

    float4 sv = hwv[(long)j * 3 + fq];
    acc.x = __fadd_rn(acc.x, __fmul_rn(sw, sv.x));
    acc.y = __fadd_rn(acc.y, __fmul_rn(sw, sv.y));
    acc.z = __fadd_rn(acc.z, __fmul_rn(sw, sv.z));
    acc.w = __fadd_rn(acc.w, __fmul_rn(sw, sv.w));
    float4 bv = ((const float4*)bias)[fq];
    acc.x = fmaxf(__fadd_rn(acc.x, bv.x), 0.f);
    acc.y = fmaxf(__fadd_rn(acc.y, bv.y), 0.f);
    acc.z = fmaxf(__fadd_rn(acc.z, bv.z), 0.f);
    acc.w = fmaxf(__fadd_rn(acc.w, bv.w), 0.f);
    ((float4*)out)[(long)np.x * 3 + fq] = acc;   // scatter to original id
}

// ---------------------------------------------------------------------------

extern "C" void kernel_launch(void* const* d_in, const int* in_sizes, int n_in,
                              void* d_out, int out_size, void* d_ws, size_t ws_size,
                              hipStream_t stream) {
    const float* x      = (const float*)d_in[0];
    const int*   ei     = (const int*)d_in[1];
    const float* ew     = (const float*)d_in[2];
    const float* W0     = (const float*)d_in[3];
    const float* b0     = (const float*)d_in[4];
    const float* Wmid   = (const float*)d_in[5];
    const float* bmid   = (const float*)d_in[6];
    const float* Wlast  = (const float*)d_in[7];
    const float* blast  = (const float*)d_in[8];

    const int N = in_sizes[0] / DIN;              // 100000
    const int E = in_sizes[2];                    // 3200000
    const int* row32 = ei;
    const int* col32 = ei + E;
    const int nblk = (E + EPB - 1) / EPB;         // 782
    const int NB   = (N + CPB - 1) / CPB;         // 782
    const int nbk  = (N + NPB - 1) / NPB;         // 98

    char* w = (char*)d_ws;
    size_t off = 0;
    auto alloc = [&](size_t bytes) -> void* {
        void* p = w + off;
        off = (off + bytes + 255) & ~(size_t)255;
        return p;
    };
    int*  T      = (int*)alloc((size_t)NB * 4);
    int*  bStart = (int*)alloc((size_t)(NB + 1) * 4);
    int*  H      = (int*)alloc((size_t)nblk * NB * 4);
    int*  O      = (int*)alloc((size_t)nblk * NB * 4);
    int*  start  = (int*)alloc((size_t)(N + 1) * 4);
    float* dis   = (float*)alloc((size_t)N * 4);
    float* selfw = (float*)alloc((size_t)N * 4);
    int*  HD     = (int*)alloc((size_t)nbk * 256 * 4);
    int*  OD     = (int*)alloc((size_t)nbk * 256 * 4);
    int*  binStart = (int*)alloc(257 * 4);
    int*  perm   = (int*)alloc((size_t)N * 4);
    int*  iperm  = (int*)alloc((size_t)N * 4);
    int4* nodepack = (int4*)alloc((size_t)N * 16);
    int2* bins   = (int2*)alloc(((size_t)E + 8) * 8); // +8 pad for agg prefetch
    float* hwA   = (float*)alloc((size_t)N * HID * 4);
    float* hwB   = (float*)alloc((size_t)N * HID * 4);
    (void)ws_size;

    hipMemsetAsync(T, 0, (size_t)NB * 4, stream);

    int gridN1 = (N + 255) / 256;

    s1_hist<<<nblk, 256, 0, stream>>>(col32, H, T, E, N, NB);
    s2b_scan<<<1, 1024, 0, stream>>>(T, bStart, NB);
    s2c_scan<<<(NB * 64 + 255) / 256, 256, 0, stream>>>(H, bStart, O, NB, nblk);
    s3_bin<<<nblk, 256, 0, stream>>>(row32, col32, ew, O, bins, E, N, NB);
    s4_sort<<<NB, 256, 0, stream>>>(bStart, bins, start, dis, selfw, E, N);
    pd1_hist<<<nbk, 256, 0, stream>>>(start, HD, N);
    pd2a_scan<<<1, 256, 0, stream>>>(HD, binStart, nbk);
    pd2b_off<<<64, 256, 0, stream>>>(HD, binStart, OD, nbk);
    pd3_fill<<<nbk, 256, 0, stream>>>(start, OD, perm, N);
    pd4_inv<<<gridN1, 256, 0, stream>>>(perm, iperm, N);
    p4_pack<<<gridN1, 256, 0, stream>>>(perm, start, selfw, nodepack, N);
    s7_norm<<<NB, 256, 0, stream>>>(bStart, bins, dis, iperm, E);
    int2* epack = bins;

    int gridN4 = (N * 4 + 255) / 256;

    gemm0<<<gridN4, 256, 0, stream>>>(x, W0, hwA, perm, N, DIN);

    // 12 fused agg+gemm layers: agg_i (bias_i) + gemm_{i+1}
    float* bufs[2] = {hwA, hwB};
    for (int i = 0; i < 11; ++i) {
        const float* bias = (i == 0) ? b0 : bmid + (size_t)(i - 1) * HID;
        const float* Wn   = Wmid + (size_t)i * HID * HID;
        agg_fused<4><<<gridN4, 256, 0, stream>>>(bufs[i & 1], epack, nodepack,
                                                 bias, Wn, bufs[(i + 1) & 1], N);
    }
    // i = 11: bias = bmid[10], next gemm = Wlast (16 -> 12)
    agg_fused<3><<<gridN4, 256, 0, stream>>>(bufs[1], epack, nodepack,
                                             bmid + (size_t)10 * HID, Wlast,
                                             bufs[0], N);
    // final agg over 12-wide hw, bias blast -> d_out (original order)
    agg_last<<<gridN4, 256, 0, stream>>>(bufs[0], epack, nodepack, blast,
                                         (float*)d_out, N);
}